// Round 21
// baseline (144.784 us; speedup 1.0000x reference)
//
#include <hip/hip_runtime.h>
#include <hip/hip_bf16.h>

#define ROI   268
#define FDIM  268
#define NB    64
#define NN    (NB*ROI)     // 17152
#define CC    32
#define DEG   32
#define KSEL  32
#define SLOPE 0.33f
#define EPSBN 1e-5f

typedef __attribute__((ext_vector_type(8)))  short bf16x8;
typedef __attribute__((ext_vector_type(4)))  float f32x4;
typedef __attribute__((ext_vector_type(16))) float f32x16;

__device__ __forceinline__ float lrelu(float h) { return h >= 0.f ? h : SLOPE * h; }

__device__ __forceinline__ unsigned short f2bf(float f) {
    union { __hip_bfloat16 h; unsigned short s; } u;
    u.h = __float2bfloat16(f);   // RNE, lowers to HW cvt
    return u.s;
}
__device__ __forceinline__ float bf2f(unsigned short h) {
    return __uint_as_float(((unsigned int)h) << 16);
}

// ================= K1: fused prep — pack(x) | packw | scalars =================
#define PREP_PACK_BLOCKS  2448
#define PREP_PACKW_BLOCKS 18
#define PREP_SCAL_BLOCKS  1072

__global__ __launch_bounds__(256) void k_prep(
    const float* __restrict__ x,
    const float* __restrict__ W1a, const float* __restrict__ W2a,
    const float* __restrict__ W3,  const float* __restrict__ b3,
    unsigned short* __restrict__ Xh, unsigned short* __restrict__ Xl,
    unsigned short* __restrict__ Wfh, unsigned short* __restrict__ Wfl,
    float* __restrict__ u3, float* __restrict__ v3, float* __restrict__ sqv)
{
    const int bid = blockIdx.x;
    const int tid = threadIdx.x;
    if (bid < PREP_PACK_BLOCKS) {
        const int gid = bid * 256 + tid;
        const int l   = gid & 63;
        const int f3  = gid >> 6;
        const int ks  = f3 % 9;
        const int bc  = f3 / 9;
        const int ct  = bc % 17;
        const int b   = bc / 17;
        const int node = ct * 16 + (l & 15);
        const int k0   = ks * 32 + (l >> 4) * 8;
        float f[8];
        #pragma unroll
        for (int j = 0; j < 8; ++j) f[j] = 0.f;
        if (node < ROI) {
            const float* row = &x[((size_t)b * ROI + node) * FDIM];
            if (k0 + 3 < FDIM) { float4 v = *(const float4*)&row[k0];     f[0]=v.x; f[1]=v.y; f[2]=v.z; f[3]=v.w; }
            if (k0 + 7 < FDIM) { float4 v = *(const float4*)&row[k0 + 4]; f[4]=v.x; f[5]=v.y; f[6]=v.z; f[7]=v.w; }
        }
        unsigned short hh[8], ll[8];
        #pragma unroll
        for (int j = 0; j < 8; ++j) {
            hh[j] = f2bf(f[j]);
            ll[j] = f2bf(f[j] - bf2f(hh[j]));
        }
        uint4 hp, lp;
        hp.x = (unsigned)hh[0] | ((unsigned)hh[1] << 16); hp.y = (unsigned)hh[2] | ((unsigned)hh[3] << 16);
        hp.z = (unsigned)hh[4] | ((unsigned)hh[5] << 16); hp.w = (unsigned)hh[6] | ((unsigned)hh[7] << 16);
        lp.x = (unsigned)ll[0] | ((unsigned)ll[1] << 16); lp.y = (unsigned)ll[2] | ((unsigned)ll[3] << 16);
        lp.z = (unsigned)ll[4] | ((unsigned)ll[5] << 16); lp.w = (unsigned)ll[6] | ((unsigned)ll[7] << 16);
        const size_t base = (size_t)f3 * 512 + l * 8;
        *(uint4*)&Xh[base] = hp;
        *(uint4*)&Xl[base] = lp;
    } else if (bid < PREP_PACK_BLOCKS + PREP_PACKW_BLOCKS) {
        const int gid = (bid - PREP_PACK_BLOCKS) * 256 + tid;   // < 4608
        const int l  = gid & 63;
        const int f3 = gid >> 6;
        const int ks = f3 % 9;
        const int mc = f3 / 9;
        const int ct = mc & 1;
        const int m  = mc >> 1;
        const int k0 = ks * 32 + (l >> 4) * 8;
        const int c  = ct * 16 + (l & 15);
        const float* W = (m < 2) ? W1a : W2a;
        const bool isU = (m & 1) == 0;
        unsigned short hh[8], ll[8];
        #pragma unroll
        for (int j = 0; j < 8; ++j) {
            const int kk = k0 + j;
            float val = 0.f;
            if (kk < FDIM) {
                float wb = W[(size_t)(FDIM + kk) * CC + c];
                val = isU ? (W[(size_t)kk * CC + c] - wb) : wb;
            }
            hh[j] = f2bf(val);
            ll[j] = f2bf(val - bf2f(hh[j]));
        }
        uint4 hp, lp;
        hp.x = (unsigned)hh[0] | ((unsigned)hh[1] << 16); hp.y = (unsigned)hh[2] | ((unsigned)hh[3] << 16);
        hp.z = (unsigned)hh[4] | ((unsigned)hh[5] << 16); hp.w = (unsigned)hh[6] | ((unsigned)hh[7] << 16);
        lp.x = (unsigned)ll[0] | ((unsigned)ll[1] << 16); lp.y = (unsigned)ll[2] | ((unsigned)ll[3] << 16);
        lp.z = (unsigned)ll[4] | ((unsigned)ll[5] << 16); lp.w = (unsigned)ll[6] | ((unsigned)ll[7] << 16);
        const size_t base = (size_t)f3 * 512 + l * 8;
        *(uint4*)&Wfh[base] = hp;
        *(uint4*)&Wfl[base] = lp;
    } else {
        const int s = bid - (PREP_PACK_BLOCKS + PREP_PACKW_BLOCKS);
        const int l = tid & 63;
        #pragma unroll
        for (int i = 0; i < 4; ++i) {
            const int n = s * 16 + i * 4 + (tid >> 6);
            const float* row = &x[(size_t)n * FDIM];
            float su = 0.f, sv = 0.f, sq = 0.f;
            #pragma unroll
            for (int t = 0; t < 4; ++t) {
                const int f = l + 64 * t;
                float xv = row[f];
                float wv = W3[FDIM + f];
                float wu = W3[f] - wv;
                su += xv * wu; sv += xv * wv; sq += xv * xv;
            }
            if (l < 12) {
                const int f = 256 + l;
                float xv = row[f];
                float wv = W3[FDIM + f];
                float wu = W3[f] - wv;
                su += xv * wu; sv += xv * wv; sq += xv * xv;
            }
            #pragma unroll
            for (int mm = 32; mm > 0; mm >>= 1) {
                su += __shfl_xor(su, mm);
                sv += __shfl_xor(sv, mm);
                sq += __shfl_xor(sq, mm);
            }
            if (l == 0) {
                u3[n] = su + b3[0];
                v3[n] = sv;
                sqv[n] = sq;
            }
        }
    }
}

// ======= K2: fused dist+proj, 576 blocks (9 per graph, XCD-congruent b = bid & 63) =======
// Each dist wave owns A-tile `at` in registers; it computes BOTH its d2 ct-strip AND
// the u/v projections for that tile (m = w>>1, both ct halves) — proj reuses the
// register-resident A-frags, eliminating the 1088 separate proj blocks entirely.
#define PD_DIST_BLOCKS 576    // 9 per graph: b = bid & 63, rt = bid >> 6 (0..8)

__global__ __launch_bounds__(512) void k_projdist(
    const unsigned short* __restrict__ Xh, const unsigned short* __restrict__ Xl,
    const unsigned short* __restrict__ Wfh, const unsigned short* __restrict__ Wfl,
    const float* __restrict__ b1a, const float* __restrict__ b2a,
    const float* __restrict__ sqv,
    float* __restrict__ u1, float* __restrict__ v1,
    float* __restrict__ u2, float* __restrict__ v2,
    int* __restrict__ knn)
{
    __shared__ float S[32][297];   // 38 KB d2 tile
    __shared__ float sqj[288];
    const int tid = threadIdx.x;
    const int l   = tid & 63;
    const int w   = tid >> 6;          // 0..7

    const int bid = blockIdx.x;
    const int b   = bid & 63;      // XCD-congruent decode
    const int rt  = bid >> 6;      // 0..8
    const int r0g = rt * 32;
    const int nrows = min(32, ROI - r0g);
    const size_t bN = (size_t)b * ROI;

    for (int t = tid; t < 288; t += 512)
        sqj[t] = (t < ROI) ? sqv[bN + t] : __builtin_inff();
    for (int t = tid; t < 32 * 16; t += 512)
        S[t >> 4][272 + (t & 15)] = __builtin_inff();   // cols never written by ct<=16

    const int a  = w & 1;
    const int at = min(rt * 2 + a, 16);     // clamped dup does identical work
    bf16x8 Ah[9], Al[9];
    {
        const size_t abase = ((size_t)(b * 17 + at) * 9) * 512 + l * 8;
        #pragma unroll
        for (int ks = 0; ks < 9; ++ks) {
            Ah[ks] = *(const bf16x8*)&Xh[abase + ks * 512];
            Al[ks] = *(const bf16x8*)&Xl[abase + ks * 512];
        }
    }
    const int rloc = (at - rt * 2) * 16 + (l >> 4) * 4;   // row within tile
    float sqr4[4];
    #pragma unroll
    for (int i = 0; i < 4; ++i) {
        const int row = r0g + rloc + i;
        sqr4[i] = (row < ROI) ? sqv[bN + row] : 0.f;
    }

    // ---- dist: d2 ct-strip for this wave ----
    for (int ct = (w >> 1); ct < 17; ct += 4) {
        const size_t bbase = ((size_t)(b * 17 + ct) * 9) * 512 + l * 8;
        f32x4 aHH = {0.f, 0.f, 0.f, 0.f};
        f32x4 aHL = {0.f, 0.f, 0.f, 0.f};
        f32x4 aLH = {0.f, 0.f, 0.f, 0.f};
        #pragma unroll
        for (int ks = 0; ks < 9; ++ks) {
            bf16x8 bh = *(const bf16x8*)&Xh[bbase + ks * 512];
            bf16x8 bl = *(const bf16x8*)&Xl[bbase + ks * 512];
            aHH = __builtin_amdgcn_mfma_f32_16x16x32_bf16(Ah[ks], bh, aHH, 0, 0, 0);
            aHL = __builtin_amdgcn_mfma_f32_16x16x32_bf16(Ah[ks], bl, aHL, 0, 0, 0);
            aLH = __builtin_amdgcn_mfma_f32_16x16x32_bf16(Al[ks], bh, aLH, 0, 0, 0);
        }
        const int col = ct * 16 + (l & 15);
        const float sj = sqj[col];
        #pragma unroll
        for (int i = 0; i < 4; ++i) {
            const float dot = (aHH[i] + aHL[i]) + aLH[i];
            S[rloc + i][col] = sqr4[i] + sj - 2.f * dot;
        }
    }

    // ---- proj for tile `at` (reuses register A-frags): wave does matrix m = w>>1 ----
    {
        const int m = w >> 1;                 // 0..3 (waves a=0/1 pairs cover all m)
        float* outp = (m == 0) ? u1 : (m == 1) ? v1 : (m == 2) ? u2 : v2;
        #pragma unroll
        for (int ct2 = 0; ct2 < 2; ++ct2) {
            const size_t wbase = ((size_t)((m * 2 + ct2) * 9)) * 512 + l * 8;
            f32x4 aHH = {0.f, 0.f, 0.f, 0.f};
            f32x4 aHL = {0.f, 0.f, 0.f, 0.f};
            f32x4 aLH = {0.f, 0.f, 0.f, 0.f};
            #pragma unroll
            for (int ks = 0; ks < 9; ++ks) {
                bf16x8 bh = *(const bf16x8*)&Wfh[wbase + ks * 512];
                bf16x8 bl = *(const bf16x8*)&Wfl[wbase + ks * 512];
                aHH = __builtin_amdgcn_mfma_f32_16x16x32_bf16(Ah[ks], bh, aHH, 0, 0, 0);
                aHL = __builtin_amdgcn_mfma_f32_16x16x32_bf16(Ah[ks], bl, aHL, 0, 0, 0);
                aLH = __builtin_amdgcn_mfma_f32_16x16x32_bf16(Al[ks], bh, aLH, 0, 0, 0);
            }
            const int ch = ct2 * 16 + (l & 15);
            float bias = 0.f;
            if (m == 0) bias = b1a[ch];
            else if (m == 2) bias = b2a[ch];
            const int r0 = (l >> 4) * 4;
            #pragma unroll
            for (int i = 0; i < 4; ++i) {
                const int node = at * 16 + r0 + i;
                if (node < ROI) {
                    const float val = ((aHH[i] + aHL[i]) + aLH[i]) + bias;
                    outp[(bN + node) * 32 + ch] = val;
                }
            }
        }
    }
    __syncthreads();

    // ---- DUAL interleaved tournament: group g handles rows g and g+16 ----
    const int grp = tid >> 5, sl = tid & 31;
    const int rowA = grp, rowB = grp + 16;
    unsigned ka[9], kb[9];
    #pragma unroll
    for (int q = 0; q < 9; ++q) {
        const int idx = q * 32 + sl;
        unsigned ba = __float_as_uint(S[rowA][idx]);
        unsigned ma = (unsigned)(((int)ba) >> 31) | 0x80000000u;
        ka[q] = ((ba ^ ma) & ~0x1FFu) | (unsigned)idx;
        unsigned bb = __float_as_uint(S[rowB][idx]);
        unsigned mb = (unsigned)(((int)bb) >> 31) | 0x80000000u;
        kb[q] = ((bb ^ mb) & ~0x1FFu) | (unsigned)idx;
    }
    #pragma unroll
    for (int i = 1; i < 9; ++i) {
        #pragma unroll
        for (int j = i; j > 0; --j) {
            unsigned loA = ka[j-1] < ka[j] ? ka[j-1] : ka[j];
            unsigned hiA = ka[j-1] < ka[j] ? ka[j]   : ka[j-1];
            ka[j-1] = loA; ka[j] = hiA;
            unsigned loB = kb[j-1] < kb[j] ? kb[j-1] : kb[j];
            unsigned hiB = kb[j-1] < kb[j] ? kb[j]   : kb[j-1];
            kb[j-1] = loB; kb[j] = hiB;
        }
    }
    unsigned keepA = 0, keepB = 0;
    #pragma unroll
    for (int it = 0; it < KSEL; ++it) {
        unsigned mA = ka[0], mB = kb[0];
        #pragma unroll
        for (int mm = 16; mm > 0; mm >>= 1) {
            unsigned oA = (unsigned)__shfl_xor((int)mA, mm, 32);
            unsigned oB = (unsigned)__shfl_xor((int)mB, mm, 32);
            mA = oA < mA ? oA : mA;
            mB = oB < mB ? oB : mB;
        }
        if (sl == it) { keepA = mA; keepB = mB; }
        const bool winA = (ka[0] == mA);
        const bool winB = (kb[0] == mB);
        #pragma unroll
        for (int q = 0; q < 8; ++q) {
            ka[q] = winA ? ka[q+1] : ka[q];
            kb[q] = winB ? kb[q+1] : kb[q];
        }
        ka[8] = winA ? 0xFFFFFFFFu : ka[8];
        kb[8] = winB ? 0xFFFFFFFFu : kb[8];
    }
    if (rowA < nrows)
        knn[(bN + r0g + rowA) * 32 + sl] = (int)bN + (int)(keepA & 0x1FFu);
    if (rowB < nrows)
        knn[(bN + r0g + rowB) * 32 + sl] = (int)bN + (int)(keepB & 0x1FFu);
}

// ======== K3: edge MLP with bf16-LDS-staged v; gcn2 reads knn ========
#define EDGE_GROUPS 10
#define EDGE_NPB 27     // ceil(268/10)
#define VSH 40          // bf16 row stride in shorts (80 B, 16B-aligned)

__global__ __launch_bounds__(256) void k_edge_fused(
    const float* __restrict__ u1, const float* __restrict__ v1,
    const float* __restrict__ W1b, const float* __restrict__ b1b,
    const int* __restrict__ ei,
    const float* __restrict__ u2, const float* __restrict__ v2,
    const float* __restrict__ W2b, const float* __restrict__ b2b,
    const int* __restrict__ knn,
    const float* __restrict__ u3, const float* __restrict__ v3,
    float* __restrict__ a1, float* __restrict__ a2, float* __restrict__ a3)
{
    __shared__ __align__(16) unsigned short vs[ROI * VSH];  // bf16 v rows
    __shared__ float vs3[ROI];

    const int tid  = threadIdx.x;
    const int l    = tid & 63;
    const int wv   = tid >> 6;
    const int half = l >> 5;
    const int e    = l & 31;
    const bool g1  = blockIdx.x < (NB * EDGE_GROUPS);
    const int rem  = g1 ? blockIdx.x : blockIdx.x - NB * EDGE_GROUPS;
    const int b    = rem / EDGE_GROUPS;
    const int q    = rem % EDGE_GROUPS;
    const int n0   = q * EDGE_NPB;
    const int cnt  = min(EDGE_NPB, ROI - n0);
    const size_t bN = (size_t)b * ROI;

    const float* u  = g1 ? u1 : u2;
    const float* v  = g1 ? v1 : v2;
    const float* Wb = g1 ? W1b : W2b;
    const float* bb = g1 ? b1b : b2b;
    const int* nbr  = g1 ? ei : knn;
    float* aout     = g1 ? a1 : a2;

    // ---- stage whole graph's v (bf16) into LDS, coalesced float4 -> 4x bf16 ----
    {
        const float* vsrc = v + bN * 32;
        for (int i = tid * 4; i < ROI * 32; i += 1024) {
            float4 vv = *(const float4*)&vsrc[i];
            const int r = i >> 5, c0 = i & 31;
            uint2 p;
            p.x = (unsigned)f2bf(vv.x) | ((unsigned)f2bf(vv.y) << 16);
            p.y = (unsigned)f2bf(vv.z) | ((unsigned)f2bf(vv.w) << 16);
            *(uint2*)&vs[r * VSH + c0] = p;
        }
        if (g1)
            for (int t = tid; t < ROI; t += 256) vs3[t] = v3[bN + t];
    }

    // ---- weights into regs ----
    union { bf16x8 v8; unsigned u4[4]; } B0, B1;
    #pragma unroll
    for (int j = 0; j < 4; ++j) {
        B0.u4[j] = (unsigned)f2bf(Wb[(half * 8 + 2*j    ) * 32 + e])
                 | ((unsigned)f2bf(Wb[(half * 8 + 2*j + 1) * 32 + e]) << 16);
        B1.u4[j] = (unsigned)f2bf(Wb[(16 + half * 8 + 2*j    ) * 32 + e])
                 | ((unsigned)f2bf(Wb[(16 + half * 8 + 2*j + 1) * 32 + e]) << 16);
    }
    const float biasc = bb[e];

    // ---- neighbor indices (local) ----
    int jns[8];
    {
        const int nper = (cnt + 3) >> 2;   // nodes per wave (<=7)
        #pragma unroll
        for (int s = 0; s < 8; ++s) jns[s] = 0;
        for (int s = 0; s < nper; ++s) {
            const int il = wv + s * 4;
            if (il < cnt)
                jns[s] = nbr[(size_t)((int)bN + n0 + il) * DEG + e] - (int)bN;
        }
    }
    __syncthreads();

    // ---- per-node edge MLP + max (v bf16 from LDS) ----
    int s = 0;
    for (int il = wv; il < cnt; il += 4, ++s) {
        const int n   = (int)bN + n0 + il;
        const int jnl = jns[s];

        float hv[16];
        #pragma unroll
        for (int ss = 0; ss < 2; ++ss) {
            const int c0 = ss * 16 + half * 8;
            float4 uv0 = *(const float4*)&u[(size_t)n * 32 + c0];
            float4 uv1 = *(const float4*)&u[(size_t)n * 32 + c0 + 4];
            bf16x8 vb = *(const bf16x8*)&vs[jnl * VSH + c0];
            const unsigned short* vbs = (const unsigned short*)&vb;
            hv[ss*8+0] = lrelu(uv0.x + bf2f(vbs[0]));
            hv[ss*8+1] = lrelu(uv0.y + bf2f(vbs[1]));
            hv[ss*8+2] = lrelu(uv0.z + bf2f(vbs[2]));
            hv[ss*8+3] = lrelu(uv0.w + bf2f(vbs[3]));
            hv[ss*8+4] = lrelu(uv1.x + bf2f(vbs[4]));
            hv[ss*8+5] = lrelu(uv1.y + bf2f(vbs[5]));
            hv[ss*8+6] = lrelu(uv1.z + bf2f(vbs[6]));
            hv[ss*8+7] = lrelu(uv1.w + bf2f(vbs[7]));
        }
        union { bf16x8 v8; unsigned u4[4]; } A0, A1;
        #pragma unroll
        for (int j = 0; j < 4; ++j) {
            A0.u4[j] = (unsigned)f2bf(hv[2*j])     | ((unsigned)f2bf(hv[2*j + 1]) << 16);
            A1.u4[j] = (unsigned)f2bf(hv[8 + 2*j]) | ((unsigned)f2bf(hv[8 + 2*j + 1]) << 16);
        }
        f32x16 acc = {0.f,0.f,0.f,0.f,0.f,0.f,0.f,0.f,0.f,0.f,0.f,0.f,0.f,0.f,0.f,0.f};
        acc = __builtin_amdgcn_mfma_f32_32x32x16_bf16(A0.v8, B0.v8, acc, 0, 0, 0);
        acc = __builtin_amdgcn_mfma_f32_32x32x16_bf16(A1.v8, B1.v8, acc, 0, 0, 0);

        float mx = acc[0];
        #pragma unroll
        for (int r = 1; r < 16; ++r) mx = fmaxf(mx, acc[r]);
        mx = fmaxf(mx, __shfl_xor(mx, 32));
        if (l < 32) aout[(size_t)n * 32 + l] = mx + biasc;

        if (g1) {
            float a3v = u3[n] + vs3[jnl];
            #pragma unroll
            for (int mm = 16; mm > 0; mm >>= 1) a3v = fmaxf(a3v, __shfl_xor(a3v, mm));
            if (l == 0) a3[n] = a3v;
        }
    }
}

// ---------------- K4: coalesced per-chunk partial BN stats for a1,a2 ----------------
__global__ __launch_bounds__(256) void k_stats1(
    const float* __restrict__ a1, const float* __restrict__ a2,
    float* __restrict__ part)
{
    const int p = blockIdx.x;
    const int tid = threadIdx.x;
    const int ch = tid & 31, sub = tid >> 5;
    const size_t base = (size_t)p * ROI;
    float s1 = 0.f, q1 = 0.f, s2 = 0.f, q2 = 0.f;
    for (int n = sub; n < ROI; n += 8) {
        float v1 = a1[(base + n) * 32 + ch];
        float v2 = a2[(base + n) * 32 + ch];
        s1 += v1; q1 += v1 * v1; s2 += v2; q2 += v2 * v2;
    }
    __shared__ float L[4][256];
    L[0][tid] = s1; L[1][tid] = q1; L[2][tid] = s2; L[3][tid] = q2;
    __syncthreads();
    if (tid < 128) {
        const int a = tid >> 5, c = tid & 31;
        float s = 0.f;
        #pragma unroll
        for (int k = 0; k < 8; ++k) s += L[a][c + 32 * k];
        part[p * 128 + a * 32 + c] = s;
    }
}

// ======== K5: pool + fc1 with fused BN finalize (per-block recompute) ========
__global__ __launch_bounds__(256) void k_pool_fc1(
    const float* __restrict__ a1, const float* __restrict__ a2, const float* __restrict__ a3,
    const float* __restrict__ part,
    const float* __restrict__ g1, const float* __restrict__ be1,
    const float* __restrict__ g2, const float* __restrict__ be2,
    const float* __restrict__ g3, const float* __restrict__ be3,
    const float* __restrict__ Wl1, const float* __restrict__ bl1,
    float* __restrict__ h1)
{
    const int b = blockIdx.x, tid = threadIdx.x;
    __shared__ float stl[130];
    __shared__ float zs[332];
    __shared__ float P[4][64];
    __shared__ float S3[256], Q3[256];

    {
        float p0 = 0.f, p1 = 0.f, p2 = 0.f, p3 = 0.f;
        float q0 = 0.f, q1 = 0.f, q2 = 0.f, q3 = 0.f;
        int n = tid;
        for (; n + 768 < NN; n += 1024) {
            float a = a3[n], bb = a3[n + 256], c = a3[n + 512], d = a3[n + 768];
            p0 += a; q0 += a * a;
            p1 += bb; q1 += bb * bb;
            p2 += c; q2 += c * c;
            p3 += d; q3 += d * d;
        }
        for (; n < NN; n += 256) { float a = a3[n]; p0 += a; q0 += a * a; }
        S3[tid] = (p0 + p1) + (p2 + p3);
        Q3[tid] = (q0 + q1) + (q2 + q3);
    }
    __syncthreads();
    for (int off = 128; off > 0; off >>= 1) {
        if (tid < off) { S3[tid] += S3[tid + off]; Q3[tid] += Q3[tid + off]; }
        __syncthreads();
    }
    if (tid < 64) {
        const int a = (tid >> 5) * 2, c = tid & 31;
        float s0 = 0.f, s1 = 0.f, q0b = 0.f, q1b = 0.f;
        for (int p = 0; p < 64; p += 2) {
            s0  += part[p * 128 + a * 32 + c];
            q0b += part[p * 128 + (a + 1) * 32 + c];
            s1  += part[(p + 1) * 128 + a * 32 + c];
            q1b += part[(p + 1) * 128 + (a + 1) * 32 + c];
        }
        float ss = s0 + s1, qq = q0b + q1b;
        float gv = (tid < 32) ? g1[c] : g2[c];
        float bv = (tid < 32) ? be1[c] : be2[c];
        float mu  = ss * (1.f / NN);
        float var = qq * (1.f / NN) - mu * mu;
        float sc  = gv * rsqrtf(var + EPSBN);
        stl[tid * 2] = sc; stl[tid * 2 + 1] = bv - mu * sc;
    }
    if (tid == 64) {
        float mu  = S3[0] * (1.f / NN);
        float var = Q3[0] * (1.f / NN) - mu * mu;
        float sc  = g3[0] * rsqrtf(var + EPSBN);
        stl[128] = sc; stl[129] = be3[0] - mu * sc;
    }
    __syncthreads();

    const int c = tid & 63, grp = tid >> 6;
    const float* src = (c < 32) ? a1 : a2;
    const int ch = c & 31;
    const float sc = stl[c * 2], sh = stl[c * 2 + 1];
    {
        const size_t rb = (size_t)b * ROI;
        float p0 = 0.f, p1 = 0.f, p2 = 0.f, p3 = 0.f;
        int i = grp;
        for (; i + 12 < ROI; i += 16) {
            p0 += lrelu(src[(rb + i)      * 32 + ch] * sc + sh);
            p1 += lrelu(src[(rb + i + 4)  * 32 + ch] * sc + sh);
            p2 += lrelu(src[(rb + i + 8)  * 32 + ch] * sc + sh);
            p3 += lrelu(src[(rb + i + 12) * 32 + ch] * sc + sh);
        }
        for (; i < ROI; i += 4)
            p0 += lrelu(src[(rb + i) * 32 + ch] * sc + sh);
        P[grp][c] = (p0 + p1) + (p2 + p3);
    }
    const float sc3 = stl[128], sh3 = stl[129];
    for (int i = tid; i < ROI; i += 256)
        zs[64 + i] = lrelu(a3[b * ROI + i] * sc3 + sh3);
    __syncthreads();
    if (tid < 64)
        zs[tid] = (P[0][tid] + P[1][tid] + P[2][tid] + P[3][tid]) * (1.f / ROI);
    __syncthreads();

    {
        float s0 = 0.f, s1 = 0.f, s2 = 0.f, s3 = 0.f;
        #pragma unroll 4
        for (int k = 0; k < 332; k += 4) {
            s0 += zs[k]     * Wl1[(size_t)k       * 256 + tid];
            s1 += zs[k + 1] * Wl1[(size_t)(k + 1) * 256 + tid];
            s2 += zs[k + 2] * Wl1[(size_t)(k + 2) * 256 + tid];
            s3 += zs[k + 3] * Wl1[(size_t)(k + 3) * 256 + tid];
        }
        h1[(size_t)b * 256 + tid] = bl1[tid] + ((s0 + s1) + (s2 + s3));
    }
}

// ======== K6: fc2 with fused batch stats ========
__global__ __launch_bounds__(128) void k_fc2s(
    const float* __restrict__ h1,
    const float* __restrict__ g4, const float* __restrict__ be4,
    const float* __restrict__ Wl2, const float* __restrict__ bl2,
    float* __restrict__ h2)
{
    const int b = blockIdx.x, tid = threadIdx.x;
    __shared__ float hs[256];
    float s0 = 0.f, q0 = 0.f, s1 = 0.f, q1 = 0.f;
    float s2 = 0.f, q2 = 0.f, s3 = 0.f, q3 = 0.f;
    for (int r = 0; r < NB; r += 2) {
        float a = h1[(size_t)r * 256 + tid];
        float c = h1[(size_t)r * 256 + tid + 128];
        float d = h1[(size_t)(r + 1) * 256 + tid];
        float e = h1[(size_t)(r + 1) * 256 + tid + 128];
        s0 += a; q0 += a * a;
        s1 += c; q1 += c * c;
        s2 += d; q2 += d * d;
        s3 += e; q3 += e * e;
    }
    {
        float ssA = s0 + s2, qqA = q0 + q2;
        float muA = ssA * (1.f / NB);
        float vaA = qqA * (1.f / NB) - muA * muA;
        float scA = g4[tid] * rsqrtf(vaA + EPSBN);
        float shA = be4[tid] - muA * scA;
        hs[tid] = lrelu(h1[(size_t)b * 256 + tid] * scA + shA);
        float ssB = s1 + s3, qqB = q1 + q3;
        float muB = ssB * (1.f / NB);
        float vaB = qqB * (1.f / NB) - muB * muB;
        float scB = g4[tid + 128] * rsqrtf(vaB + EPSBN);
        float shB = be4[tid + 128] - muB * scB;
        hs[tid + 128] = lrelu(h1[(size_t)b * 256 + tid + 128] * scB + shB);
    }
    __syncthreads();
    float s0b = 0.f, s1b = 0.f, s2b = 0.f, s3b = 0.f;
    #pragma unroll 4
    for (int k = 0; k < 256; k += 4) {
        s0b += hs[k]     * Wl2[(size_t)k       * 128 + tid];
        s1b += hs[k + 1] * Wl2[(size_t)(k + 1) * 128 + tid];
        s2b += hs[k + 2] * Wl2[(size_t)(k + 2) * 128 + tid];
        s3b += hs[k + 3] * Wl2[(size_t)(k + 3) * 128 + tid];
    }
    h2[(size_t)b * 128 + tid] = bl2[tid] + ((s0b + s1b) + (s2b + s3b));
}

// ======== K7: fc3 with fused batch stats (single block) ========
__global__ __launch_bounds__(128) void k_fc3s(
    const float* __restrict__ h2,
    const float* __restrict__ g5, const float* __restrict__ be5,
    const float* __restrict__ Wl3, const float* __restrict__ bl3,
    float* __restrict__ out)
{
    const int tid = threadIdx.x;
    __shared__ float T[64][133];
    float s0 = 0.f, q0 = 0.f, s1 = 0.f, q1 = 0.f;
    for (int r = 0; r < NB; r += 2) {
        float a = h2[(size_t)r * 128 + tid];
        float b = h2[(size_t)(r + 1) * 128 + tid];
        s0 += a; q0 += a * a;
        s1 += b; q1 += b * b;
    }
    float ss = s0 + s1, qq = q0 + q1;
    float mu  = ss * (1.f / NB);
    float var = qq * (1.f / NB) - mu * mu;
    float sc  = g5[tid] * rsqrtf(var + EPSBN);
    float sh  = be5[tid] - mu * sc;
    const float w3 = Wl3[tid];
    for (int r = 0; r < NB; ++r)
        T[r][tid] = lrelu(h2[(size_t)r * 128 + tid] * sc + sh) * w3;
    __syncthreads();
    if (tid < 64) {
        float a0 = 0.f, a1 = 0.f, a2 = 0.f, a3 = 0.f;
        #pragma unroll 4
        for (int c = 0; c < 128; c += 4) {
            a0 += T[tid][c];
            a1 += T[tid][c + 1];
            a2 += T[tid][c + 2];
            a3 += T[tid][c + 3];
        }
        out[tid] = bl3[0] + ((a0 + a1) + (a2 + a3));
    }
}

extern "C" void kernel_launch(void* const* d_in, const int* in_sizes, int n_in,
                              void* d_out, int out_size, void* d_ws, size_t ws_size,
                              hipStream_t stream)
{
    (void)in_sizes; (void)n_in; (void)out_size; (void)ws_size;
    const float* x   = (const float*)d_in[0];
    const int*   ei  = (const int*)d_in[1];
    const float* W1a = (const float*)d_in[3];
    const float* b1a = (const float*)d_in[4];
    const float* W1b = (const float*)d_in[5];
    const float* b1b = (const float*)d_in[6];
    const float* g1  = (const float*)d_in[7];
    const float* be1 = (const float*)d_in[8];
    const float* W2a = (const float*)d_in[9];
    const float* b2a = (const float*)d_in[10];
    const float* W2b = (const float*)d_in[11];
    const float* b2b = (const float*)d_in[12];
    const float* g2  = (const float*)d_in[13];
    const float* be2 = (const float*)d_in[14];
    const float* W3  = (const float*)d_in[15];
    const float* b3  = (const float*)d_in[16];
    const float* g3  = (const float*)d_in[17];
    const float* be3 = (const float*)d_in[18];
    const float* Wl1 = (const float*)d_in[19];
    const float* bl1 = (const float*)d_in[20];
    const float* g4  = (const float*)d_in[21];
    const float* be4 = (const float*)d_in[22];
    const float* Wl2 = (const float*)d_in[23];
    const float* bl2 = (const float*)d_in[24];
    const float* g5  = (const float*)d_in[25];
    const float* be5 = (const float*)d_in[26];
    const float* Wl3 = (const float*)d_in[27];
    const float* bl3 = (const float*)d_in[28];

    float* ws  = (float*)d_ws;
    float* u1  = ws;
    float* v1  = u1 + (size_t)NN * 32;
    float* u2  = v1 + (size_t)NN * 32;
    float* v2  = u2 + (size_t)NN * 32;
    float* u3  = v2 + (size_t)NN * 32;
    float* v3  = u3 + NN;
    float* sqv = v3 + NN;
    float* a1  = sqv + NN;
    float* a2  = a1 + (size_t)NN * 32;
    float* a3  = a2 + (size_t)NN * 32;
    float* h1  = a3 + NN;
    float* h2  = h1 + (size_t)NB * 256;
    float* part = h2 + (size_t)NB * 128;            // [64][128]
    int*   knn = (int*)(part + 64 * 128);
    unsigned short* Xh = (unsigned short*)(((uintptr_t)(knn + (size_t)NN * 32) + 255) & ~(uintptr_t)255);
    unsigned short* Xl = Xh + (size_t)64 * 17 * 9 * 512;
    unsigned short* Wfh = Xl + (size_t)64 * 17 * 9 * 512;
    unsigned short* Wfl = Wfh + (size_t)8 * 9 * 512;

    k_prep<<<PREP_PACK_BLOCKS + PREP_PACKW_BLOCKS + PREP_SCAL_BLOCKS, 256, 0, stream>>>(
        x, W1a, W2a, W3, b3, Xh, Xl, Wfh, Wfl, u3, v3, sqv);
    k_projdist<<<PD_DIST_BLOCKS, 512, 0, stream>>>(
        Xh, Xl, Wfh, Wfl, b1a, b2a, sqv, u1, v1, u2, v2, knn);
    k_edge_fused<<<2 * NB * EDGE_GROUPS, 256, 0, stream>>>(
        u1, v1, W1b, b1b, ei, u2, v2, W2b, b2b, knn, u3, v3, a1, a2, a3);
    k_stats1<<<64, 256, 0, stream>>>(a1, a2, part);
    k_pool_fc1<<<NB, 256, 0, stream>>>(a1, a2, a3, part, g1, be1, g2, be2, g3, be3,
                                       Wl1, bl1, h1);
    k_fc2s<<<NB, 128, 0, stream>>>(h1, g4, be4, Wl2, bl2, h2);
    k_fc3s<<<1, 128, 0, stream>>>(h2, g5, be5, Wl3, bl3, (float*)d_out);
}

// Round 22
// 131.152 us; speedup vs baseline: 1.1039x; 1.1039x over previous
//
#include <hip/hip_runtime.h>
#include <hip/hip_bf16.h>

#define ROI   268
#define FDIM  268
#define NB    64
#define NN    (NB*ROI)     // 17152
#define CC    32
#define DEG   32
#define KSEL  32
#define SLOPE 0.33f
#define EPSBN 1e-5f

typedef __attribute__((ext_vector_type(8)))  short bf16x8;
typedef __attribute__((ext_vector_type(4)))  float f32x4;
typedef __attribute__((ext_vector_type(16))) float f32x16;

__device__ __forceinline__ float lrelu(float h) { return h >= 0.f ? h : SLOPE * h; }

__device__ __forceinline__ unsigned short f2bf(float f) {
    union { __hip_bfloat16 h; unsigned short s; } u;
    u.h = __float2bfloat16(f);   // RNE, lowers to HW cvt
    return u.s;
}
__device__ __forceinline__ float bf2f(unsigned short h) {
    return __uint_as_float(((unsigned int)h) << 16);
}

// ================= K1: fused prep — pack(x) | packw | scalars =================
#define PREP_PACK_BLOCKS  2448
#define PREP_PACKW_BLOCKS 18
#define PREP_SCAL_BLOCKS  1072

__global__ __launch_bounds__(256) void k_prep(
    const float* __restrict__ x,
    const float* __restrict__ W1a, const float* __restrict__ W2a,
    const float* __restrict__ W3,  const float* __restrict__ b3,
    unsigned short* __restrict__ Xh, unsigned short* __restrict__ Xl,
    unsigned short* __restrict__ Wfh, unsigned short* __restrict__ Wfl,
    float* __restrict__ u3, float* __restrict__ v3, float* __restrict__ sqv)
{
    const int bid = blockIdx.x;
    const int tid = threadIdx.x;
    if (bid < PREP_PACK_BLOCKS) {
        const int gid = bid * 256 + tid;
        const int l   = gid & 63;
        const int f3  = gid >> 6;
        const int ks  = f3 % 9;
        const int bc  = f3 / 9;
        const int ct  = bc % 17;
        const int b   = bc / 17;
        const int node = ct * 16 + (l & 15);
        const int k0   = ks * 32 + (l >> 4) * 8;
        float f[8];
        #pragma unroll
        for (int j = 0; j < 8; ++j) f[j] = 0.f;
        if (node < ROI) {
            const float* row = &x[((size_t)b * ROI + node) * FDIM];
            if (k0 + 3 < FDIM) { float4 v = *(const float4*)&row[k0];     f[0]=v.x; f[1]=v.y; f[2]=v.z; f[3]=v.w; }
            if (k0 + 7 < FDIM) { float4 v = *(const float4*)&row[k0 + 4]; f[4]=v.x; f[5]=v.y; f[6]=v.z; f[7]=v.w; }
        }
        unsigned short hh[8], ll[8];
        #pragma unroll
        for (int j = 0; j < 8; ++j) {
            hh[j] = f2bf(f[j]);
            ll[j] = f2bf(f[j] - bf2f(hh[j]));
        }
        uint4 hp, lp;
        hp.x = (unsigned)hh[0] | ((unsigned)hh[1] << 16); hp.y = (unsigned)hh[2] | ((unsigned)hh[3] << 16);
        hp.z = (unsigned)hh[4] | ((unsigned)hh[5] << 16); hp.w = (unsigned)hh[6] | ((unsigned)hh[7] << 16);
        lp.x = (unsigned)ll[0] | ((unsigned)ll[1] << 16); lp.y = (unsigned)ll[2] | ((unsigned)ll[3] << 16);
        lp.z = (unsigned)ll[4] | ((unsigned)ll[5] << 16); lp.w = (unsigned)ll[6] | ((unsigned)ll[7] << 16);
        const size_t base = (size_t)f3 * 512 + l * 8;
        *(uint4*)&Xh[base] = hp;
        *(uint4*)&Xl[base] = lp;
    } else if (bid < PREP_PACK_BLOCKS + PREP_PACKW_BLOCKS) {
        const int gid = (bid - PREP_PACK_BLOCKS) * 256 + tid;   // < 4608
        const int l  = gid & 63;
        const int f3 = gid >> 6;
        const int ks = f3 % 9;
        const int mc = f3 / 9;
        const int ct = mc & 1;
        const int m  = mc >> 1;
        const int k0 = ks * 32 + (l >> 4) * 8;
        const int c  = ct * 16 + (l & 15);
        const float* W = (m < 2) ? W1a : W2a;
        const bool isU = (m & 1) == 0;
        unsigned short hh[8], ll[8];
        #pragma unroll
        for (int j = 0; j < 8; ++j) {
            const int kk = k0 + j;
            float val = 0.f;
            if (kk < FDIM) {
                float wb = W[(size_t)(FDIM + kk) * CC + c];
                val = isU ? (W[(size_t)kk * CC + c] - wb) : wb;
            }
            hh[j] = f2bf(val);
            ll[j] = f2bf(val - bf2f(hh[j]));
        }
        uint4 hp, lp;
        hp.x = (unsigned)hh[0] | ((unsigned)hh[1] << 16); hp.y = (unsigned)hh[2] | ((unsigned)hh[3] << 16);
        hp.z = (unsigned)hh[4] | ((unsigned)hh[5] << 16); hp.w = (unsigned)hh[6] | ((unsigned)hh[7] << 16);
        lp.x = (unsigned)ll[0] | ((unsigned)ll[1] << 16); lp.y = (unsigned)ll[2] | ((unsigned)ll[3] << 16);
        lp.z = (unsigned)ll[4] | ((unsigned)ll[5] << 16); lp.w = (unsigned)ll[6] | ((unsigned)ll[7] << 16);
        const size_t base = (size_t)f3 * 512 + l * 8;
        *(uint4*)&Wfh[base] = hp;
        *(uint4*)&Wfl[base] = lp;
    } else {
        const int s = bid - (PREP_PACK_BLOCKS + PREP_PACKW_BLOCKS);
        const int l = tid & 63;
        #pragma unroll
        for (int i = 0; i < 4; ++i) {
            const int n = s * 16 + i * 4 + (tid >> 6);
            const float* row = &x[(size_t)n * FDIM];
            float su = 0.f, sv = 0.f, sq = 0.f;
            #pragma unroll
            for (int t = 0; t < 4; ++t) {
                const int f = l + 64 * t;
                float xv = row[f];
                float wv = W3[FDIM + f];
                float wu = W3[f] - wv;
                su += xv * wu; sv += xv * wv; sq += xv * xv;
            }
            if (l < 12) {
                const int f = 256 + l;
                float xv = row[f];
                float wv = W3[FDIM + f];
                float wu = W3[f] - wv;
                su += xv * wu; sv += xv * wv; sq += xv * xv;
            }
            #pragma unroll
            for (int mm = 32; mm > 0; mm >>= 1) {
                su += __shfl_xor(su, mm);
                sv += __shfl_xor(sv, mm);
                sq += __shfl_xor(sq, mm);
            }
            if (l == 0) {
                u3[n] = su + b3[0];
                v3[n] = sv;
                sqv[n] = sq;
            }
        }
    }
}

// ======= K2: dist+select in LDS (blocks [0,576)) | proj (blocks [576,1664)) =======
// dist block = (graph, 32-row tile); XCD-congruent b = bid & 63. Tournament runs
// TWO interleaved row-chains per 32-lane group (2x shfl-chain ILP on the DS pipe).
#define PD_DIST_BLOCKS 576    // 9 per graph: b = bid & 63, rt = bid >> 6 (0..8)
#define PD_PROJ_BLOCKS 1088   // 17 per graph: b = idx & 63, ctn = idx >> 6

__global__ __launch_bounds__(512) void k_projdist(
    const unsigned short* __restrict__ Xh, const unsigned short* __restrict__ Xl,
    const unsigned short* __restrict__ Wfh, const unsigned short* __restrict__ Wfl,
    const float* __restrict__ b1a, const float* __restrict__ b2a,
    const float* __restrict__ sqv,
    float* __restrict__ u1, float* __restrict__ v1,
    float* __restrict__ u2, float* __restrict__ v2,
    int* __restrict__ knn)
{
    __shared__ float S[32][297];   // 38 KB d2 tile
    __shared__ float sqj[288];
    const int tid = threadIdx.x;
    const int l   = tid & 63;
    const int w   = tid >> 6;          // 0..7

    if (blockIdx.x >= PD_DIST_BLOCKS) {
        // ---------------- proj: u1,v1,u2,v2 via MFMA; wave = (m, ct) ----------------
        const int idx  = blockIdx.x - PD_DIST_BLOCKS;   // 0..1087
        const int b    = idx & 63;
        const int ctn  = idx >> 6;                      // 0..16
        const int tile = b * 17 + ctn;
        const int m    = w >> 1;
        const int ct   = w & 1;
        bf16x8 Ah[9], Al[9];
        {
            const size_t abase = (size_t)tile * 9 * 512 + l * 8;
            #pragma unroll
            for (int ks = 0; ks < 9; ++ks) {
                Ah[ks] = *(const bf16x8*)&Xh[abase + ks * 512];
                Al[ks] = *(const bf16x8*)&Xl[abase + ks * 512];
            }
        }
        float* outp = (m == 0) ? u1 : (m == 1) ? v1 : (m == 2) ? u2 : v2;
        const size_t wbase = ((size_t)((m * 2 + ct) * 9)) * 512 + l * 8;
        f32x4 aHH = {0.f, 0.f, 0.f, 0.f};
        f32x4 aHL = {0.f, 0.f, 0.f, 0.f};
        f32x4 aLH = {0.f, 0.f, 0.f, 0.f};
        #pragma unroll
        for (int ks = 0; ks < 9; ++ks) {
            bf16x8 bh = *(const bf16x8*)&Wfh[wbase + ks * 512];
            bf16x8 bl = *(const bf16x8*)&Wfl[wbase + ks * 512];
            aHH = __builtin_amdgcn_mfma_f32_16x16x32_bf16(Ah[ks], bh, aHH, 0, 0, 0);
            aHL = __builtin_amdgcn_mfma_f32_16x16x32_bf16(Ah[ks], bl, aHL, 0, 0, 0);
            aLH = __builtin_amdgcn_mfma_f32_16x16x32_bf16(Al[ks], bh, aLH, 0, 0, 0);
        }
        f32x4 acc;
        #pragma unroll
        for (int i = 0; i < 4; ++i) acc[i] = (aHH[i] + aHL[i]) + aLH[i];
        const int ch = ct * 16 + (l & 15);
        float bias = 0.f;
        if (m == 0) bias = b1a[ch];
        else if (m == 2) bias = b2a[ch];
        const int r0 = (l >> 4) * 4;
        #pragma unroll
        for (int i = 0; i < 4; ++i) {
            const int node = ctn * 16 + r0 + i;
            if (node < ROI)
                outp[((size_t)b * ROI + node) * 32 + ch] = acc[i] + bias;
        }
        return;
    }

    // ---------------- dist rows rt*32..+31 of graph b, d2 in LDS ----------------
    const int bid = blockIdx.x;
    const int b   = bid & 63;      // XCD-congruent decode
    const int rt  = bid >> 6;      // 0..8
    const int r0g = rt * 32;
    const int nrows = min(32, ROI - r0g);
    const size_t bN = (size_t)b * ROI;

    for (int t = tid; t < 288; t += 512)
        sqj[t] = (t < ROI) ? sqv[bN + t] : __builtin_inff();
    for (int t = tid; t < 32 * 16; t += 512)
        S[t >> 4][272 + (t & 15)] = __builtin_inff();   // cols never written by ct<=16

    const int a  = w & 1;
    const int at = min(rt * 2 + a, 16);     // clamped dup writes identical values
    bf16x8 Ah[9], Al[9];
    {
        const size_t abase = ((size_t)(b * 17 + at) * 9) * 512 + l * 8;
        #pragma unroll
        for (int ks = 0; ks < 9; ++ks) {
            Ah[ks] = *(const bf16x8*)&Xh[abase + ks * 512];
            Al[ks] = *(const bf16x8*)&Xl[abase + ks * 512];
        }
    }
    const int rloc = (at - rt * 2) * 16 + (l >> 4) * 4;   // row within tile
    float sqr4[4];
    #pragma unroll
    for (int i = 0; i < 4; ++i) {
        const int row = r0g + rloc + i;
        sqr4[i] = (row < ROI) ? sqv[bN + row] : 0.f;
    }

    for (int ct = (w >> 1); ct < 17; ct += 4) {
        const size_t bbase = ((size_t)(b * 17 + ct) * 9) * 512 + l * 8;
        f32x4 aHH = {0.f, 0.f, 0.f, 0.f};
        f32x4 aHL = {0.f, 0.f, 0.f, 0.f};
        f32x4 aLH = {0.f, 0.f, 0.f, 0.f};
        #pragma unroll
        for (int ks = 0; ks < 9; ++ks) {
            bf16x8 bh = *(const bf16x8*)&Xh[bbase + ks * 512];
            bf16x8 bl = *(const bf16x8*)&Xl[bbase + ks * 512];
            aHH = __builtin_amdgcn_mfma_f32_16x16x32_bf16(Ah[ks], bh, aHH, 0, 0, 0);
            aHL = __builtin_amdgcn_mfma_f32_16x16x32_bf16(Ah[ks], bl, aHL, 0, 0, 0);
            aLH = __builtin_amdgcn_mfma_f32_16x16x32_bf16(Al[ks], bh, aLH, 0, 0, 0);
        }
        const int col = ct * 16 + (l & 15);
        const float sj = sqj[col];
        #pragma unroll
        for (int i = 0; i < 4; ++i) {
            const float dot = (aHH[i] + aHL[i]) + aLH[i];
            S[rloc + i][col] = sqr4[i] + sj - 2.f * dot;
        }
    }
    __syncthreads();

    // ---- DUAL interleaved tournament: group g handles rows g and g+16 ----
    const int grp = tid >> 5, sl = tid & 31;
    const int rowA = grp, rowB = grp + 16;
    unsigned ka[9], kb[9];
    #pragma unroll
    for (int q = 0; q < 9; ++q) {
        const int idx = q * 32 + sl;
        unsigned ba = __float_as_uint(S[rowA][idx]);
        unsigned ma = (unsigned)(((int)ba) >> 31) | 0x80000000u;
        ka[q] = ((ba ^ ma) & ~0x1FFu) | (unsigned)idx;
        unsigned bb = __float_as_uint(S[rowB][idx]);
        unsigned mb = (unsigned)(((int)bb) >> 31) | 0x80000000u;
        kb[q] = ((bb ^ mb) & ~0x1FFu) | (unsigned)idx;
    }
    #pragma unroll
    for (int i = 1; i < 9; ++i) {
        #pragma unroll
        for (int j = i; j > 0; --j) {
            unsigned loA = ka[j-1] < ka[j] ? ka[j-1] : ka[j];
            unsigned hiA = ka[j-1] < ka[j] ? ka[j]   : ka[j-1];
            ka[j-1] = loA; ka[j] = hiA;
            unsigned loB = kb[j-1] < kb[j] ? kb[j-1] : kb[j];
            unsigned hiB = kb[j-1] < kb[j] ? kb[j]   : kb[j-1];
            kb[j-1] = loB; kb[j] = hiB;
        }
    }
    unsigned keepA = 0, keepB = 0;
    #pragma unroll
    for (int it = 0; it < KSEL; ++it) {
        unsigned mA = ka[0], mB = kb[0];
        #pragma unroll
        for (int mm = 16; mm > 0; mm >>= 1) {
            unsigned oA = (unsigned)__shfl_xor((int)mA, mm, 32);
            unsigned oB = (unsigned)__shfl_xor((int)mB, mm, 32);
            mA = oA < mA ? oA : mA;
            mB = oB < mB ? oB : mB;
        }
        if (sl == it) { keepA = mA; keepB = mB; }
        const bool winA = (ka[0] == mA);
        const bool winB = (kb[0] == mB);
        #pragma unroll
        for (int q = 0; q < 8; ++q) {
            ka[q] = winA ? ka[q+1] : ka[q];
            kb[q] = winB ? kb[q+1] : kb[q];
        }
        ka[8] = winA ? 0xFFFFFFFFu : ka[8];
        kb[8] = winB ? 0xFFFFFFFFu : kb[8];
    }
    if (rowA < nrows)
        knn[(bN + r0g + rowA) * 32 + sl] = (int)bN + (int)(keepA & 0x1FFu);
    if (rowB < nrows)
        knn[(bN + r0g + rowB) * 32 + sl] = (int)bN + (int)(keepB & 0x1FFu);
}

// ======== K3: edge MLP with bf16-LDS-staged v; gcn2 reads knn ========
#define EDGE_GROUPS 10
#define EDGE_NPB 27     // ceil(268/10)
#define VSH 40          // bf16 row stride in shorts (80 B, 16B-aligned)

__global__ __launch_bounds__(256) void k_edge_fused(
    const float* __restrict__ u1, const float* __restrict__ v1,
    const float* __restrict__ W1b, const float* __restrict__ b1b,
    const int* __restrict__ ei,
    const float* __restrict__ u2, const float* __restrict__ v2,
    const float* __restrict__ W2b, const float* __restrict__ b2b,
    const int* __restrict__ knn,
    const float* __restrict__ u3, const float* __restrict__ v3,
    float* __restrict__ a1, float* __restrict__ a2, float* __restrict__ a3)
{
    __shared__ __align__(16) unsigned short vs[ROI * VSH];  // bf16 v rows
    __shared__ float vs3[ROI];

    const int tid  = threadIdx.x;
    const int l    = tid & 63;
    const int wv   = tid >> 6;
    const int half = l >> 5;
    const int e    = l & 31;
    const bool g1  = blockIdx.x < (NB * EDGE_GROUPS);
    const int rem  = g1 ? blockIdx.x : blockIdx.x - NB * EDGE_GROUPS;
    const int b    = rem / EDGE_GROUPS;
    const int q    = rem % EDGE_GROUPS;
    const int n0   = q * EDGE_NPB;
    const int cnt  = min(EDGE_NPB, ROI - n0);
    const size_t bN = (size_t)b * ROI;

    const float* u  = g1 ? u1 : u2;
    const float* v  = g1 ? v1 : v2;
    const float* Wb = g1 ? W1b : W2b;
    const float* bb = g1 ? b1b : b2b;
    const int* nbr  = g1 ? ei : knn;
    float* aout     = g1 ? a1 : a2;

    // ---- stage whole graph's v (bf16) into LDS, coalesced float4 -> 4x bf16 ----
    {
        const float* vsrc = v + bN * 32;
        for (int i = tid * 4; i < ROI * 32; i += 1024) {
            float4 vv = *(const float4*)&vsrc[i];
            const int r = i >> 5, c0 = i & 31;
            uint2 p;
            p.x = (unsigned)f2bf(vv.x) | ((unsigned)f2bf(vv.y) << 16);
            p.y = (unsigned)f2bf(vv.z) | ((unsigned)f2bf(vv.w) << 16);
            *(uint2*)&vs[r * VSH + c0] = p;
        }
        if (g1)
            for (int t = tid; t < ROI; t += 256) vs3[t] = v3[bN + t];
    }

    // ---- weights into regs ----
    union { bf16x8 v8; unsigned u4[4]; } B0, B1;
    #pragma unroll
    for (int j = 0; j < 4; ++j) {
        B0.u4[j] = (unsigned)f2bf(Wb[(half * 8 + 2*j    ) * 32 + e])
                 | ((unsigned)f2bf(Wb[(half * 8 + 2*j + 1) * 32 + e]) << 16);
        B1.u4[j] = (unsigned)f2bf(Wb[(16 + half * 8 + 2*j    ) * 32 + e])
                 | ((unsigned)f2bf(Wb[(16 + half * 8 + 2*j + 1) * 32 + e]) << 16);
    }
    const float biasc = bb[e];

    // ---- neighbor indices (local) ----
    int jns[8];
    {
        const int nper = (cnt + 3) >> 2;   // nodes per wave (<=7)
        #pragma unroll
        for (int s = 0; s < 8; ++s) jns[s] = 0;
        for (int s = 0; s < nper; ++s) {
            const int il = wv + s * 4;
            if (il < cnt)
                jns[s] = nbr[(size_t)((int)bN + n0 + il) * DEG + e] - (int)bN;
        }
    }
    __syncthreads();

    // ---- per-node edge MLP + max (v bf16 from LDS) ----
    int s = 0;
    for (int il = wv; il < cnt; il += 4, ++s) {
        const int n   = (int)bN + n0 + il;
        const int jnl = jns[s];

        float hv[16];
        #pragma unroll
        for (int ss = 0; ss < 2; ++ss) {
            const int c0 = ss * 16 + half * 8;
            float4 uv0 = *(const float4*)&u[(size_t)n * 32 + c0];
            float4 uv1 = *(const float4*)&u[(size_t)n * 32 + c0 + 4];
            bf16x8 vb = *(const bf16x8*)&vs[jnl * VSH + c0];
            const unsigned short* vbs = (const unsigned short*)&vb;
            hv[ss*8+0] = lrelu(uv0.x + bf2f(vbs[0]));
            hv[ss*8+1] = lrelu(uv0.y + bf2f(vbs[1]));
            hv[ss*8+2] = lrelu(uv0.z + bf2f(vbs[2]));
            hv[ss*8+3] = lrelu(uv0.w + bf2f(vbs[3]));
            hv[ss*8+4] = lrelu(uv1.x + bf2f(vbs[4]));
            hv[ss*8+5] = lrelu(uv1.y + bf2f(vbs[5]));
            hv[ss*8+6] = lrelu(uv1.z + bf2f(vbs[6]));
            hv[ss*8+7] = lrelu(uv1.w + bf2f(vbs[7]));
        }
        union { bf16x8 v8; unsigned u4[4]; } A0, A1;
        #pragma unroll
        for (int j = 0; j < 4; ++j) {
            A0.u4[j] = (unsigned)f2bf(hv[2*j])     | ((unsigned)f2bf(hv[2*j + 1]) << 16);
            A1.u4[j] = (unsigned)f2bf(hv[8 + 2*j]) | ((unsigned)f2bf(hv[8 + 2*j + 1]) << 16);
        }
        f32x16 acc = {0.f,0.f,0.f,0.f,0.f,0.f,0.f,0.f,0.f,0.f,0.f,0.f,0.f,0.f,0.f,0.f};
        acc = __builtin_amdgcn_mfma_f32_32x32x16_bf16(A0.v8, B0.v8, acc, 0, 0, 0);
        acc = __builtin_amdgcn_mfma_f32_32x32x16_bf16(A1.v8, B1.v8, acc, 0, 0, 0);

        float mx = acc[0];
        #pragma unroll
        for (int r = 1; r < 16; ++r) mx = fmaxf(mx, acc[r]);
        mx = fmaxf(mx, __shfl_xor(mx, 32));
        if (l < 32) aout[(size_t)n * 32 + l] = mx + biasc;

        if (g1) {
            float a3v = u3[n] + vs3[jnl];
            #pragma unroll
            for (int mm = 16; mm > 0; mm >>= 1) a3v = fmaxf(a3v, __shfl_xor(a3v, mm));
            if (l == 0) a3[n] = a3v;
        }
    }
}

// ---------------- K4: coalesced per-chunk partial BN stats for a1,a2 ----------------
__global__ __launch_bounds__(256) void k_stats1(
    const float* __restrict__ a1, const float* __restrict__ a2,
    float* __restrict__ part)
{
    const int p = blockIdx.x;
    const int tid = threadIdx.x;
    const int ch = tid & 31, sub = tid >> 5;
    const size_t base = (size_t)p * ROI;
    float s1 = 0.f, q1 = 0.f, s2 = 0.f, q2 = 0.f;
    for (int n = sub; n < ROI; n += 8) {
        float v1 = a1[(base + n) * 32 + ch];
        float v2 = a2[(base + n) * 32 + ch];
        s1 += v1; q1 += v1 * v1; s2 += v2; q2 += v2 * v2;
    }
    __shared__ float L[4][256];
    L[0][tid] = s1; L[1][tid] = q1; L[2][tid] = s2; L[3][tid] = q2;
    __syncthreads();
    if (tid < 128) {
        const int a = tid >> 5, c = tid & 31;
        float s = 0.f;
        #pragma unroll
        for (int k = 0; k < 8; ++k) s += L[a][c + 32 * k];
        part[p * 128 + a * 32 + c] = s;
    }
}

// ======== K5: pool + fc1 with fused BN finalize (per-block recompute) ========
__global__ __launch_bounds__(256) void k_pool_fc1(
    const float* __restrict__ a1, const float* __restrict__ a2, const float* __restrict__ a3,
    const float* __restrict__ part,
    const float* __restrict__ g1, const float* __restrict__ be1,
    const float* __restrict__ g2, const float* __restrict__ be2,
    const float* __restrict__ g3, const float* __restrict__ be3,
    const float* __restrict__ Wl1, const float* __restrict__ bl1,
    float* __restrict__ h1)
{
    const int b = blockIdx.x, tid = threadIdx.x;
    __shared__ float stl[130];
    __shared__ float zs[332];
    __shared__ float P[4][64];
    __shared__ float S3[256], Q3[256];

    {
        float p0 = 0.f, p1 = 0.f, p2 = 0.f, p3 = 0.f;
        float q0 = 0.f, q1 = 0.f, q2 = 0.f, q3 = 0.f;
        int n = tid;
        for (; n + 768 < NN; n += 1024) {
            float a = a3[n], bb = a3[n + 256], c = a3[n + 512], d = a3[n + 768];
            p0 += a; q0 += a * a;
            p1 += bb; q1 += bb * bb;
            p2 += c; q2 += c * c;
            p3 += d; q3 += d * d;
        }
        for (; n < NN; n += 256) { float a = a3[n]; p0 += a; q0 += a * a; }
        S3[tid] = (p0 + p1) + (p2 + p3);
        Q3[tid] = (q0 + q1) + (q2 + q3);
    }
    __syncthreads();
    for (int off = 128; off > 0; off >>= 1) {
        if (tid < off) { S3[tid] += S3[tid + off]; Q3[tid] += Q3[tid + off]; }
        __syncthreads();
    }
    if (tid < 64) {
        const int a = (tid >> 5) * 2, c = tid & 31;
        float s0 = 0.f, s1 = 0.f, q0b = 0.f, q1b = 0.f;
        for (int p = 0; p < 64; p += 2) {
            s0  += part[p * 128 + a * 32 + c];
            q0b += part[p * 128 + (a + 1) * 32 + c];
            s1  += part[(p + 1) * 128 + a * 32 + c];
            q1b += part[(p + 1) * 128 + (a + 1) * 32 + c];
        }
        float ss = s0 + s1, qq = q0b + q1b;
        float gv = (tid < 32) ? g1[c] : g2[c];
        float bv = (tid < 32) ? be1[c] : be2[c];
        float mu  = ss * (1.f / NN);
        float var = qq * (1.f / NN) - mu * mu;
        float sc  = gv * rsqrtf(var + EPSBN);
        stl[tid * 2] = sc; stl[tid * 2 + 1] = bv - mu * sc;
    }
    if (tid == 64) {
        float mu  = S3[0] * (1.f / NN);
        float var = Q3[0] * (1.f / NN) - mu * mu;
        float sc  = g3[0] * rsqrtf(var + EPSBN);
        stl[128] = sc; stl[129] = be3[0] - mu * sc;
    }
    __syncthreads();

    const int c = tid & 63, grp = tid >> 6;
    const float* src = (c < 32) ? a1 : a2;
    const int ch = c & 31;
    const float sc = stl[c * 2], sh = stl[c * 2 + 1];
    {
        const size_t rb = (size_t)b * ROI;
        float p0 = 0.f, p1 = 0.f, p2 = 0.f, p3 = 0.f;
        int i = grp;
        for (; i + 12 < ROI; i += 16) {
            p0 += lrelu(src[(rb + i)      * 32 + ch] * sc + sh);
            p1 += lrelu(src[(rb + i + 4)  * 32 + ch] * sc + sh);
            p2 += lrelu(src[(rb + i + 8)  * 32 + ch] * sc + sh);
            p3 += lrelu(src[(rb + i + 12) * 32 + ch] * sc + sh);
        }
        for (; i < ROI; i += 4)
            p0 += lrelu(src[(rb + i) * 32 + ch] * sc + sh);
        P[grp][c] = (p0 + p1) + (p2 + p3);
    }
    const float sc3 = stl[128], sh3 = stl[129];
    for (int i = tid; i < ROI; i += 256)
        zs[64 + i] = lrelu(a3[b * ROI + i] * sc3 + sh3);
    __syncthreads();
    if (tid < 64)
        zs[tid] = (P[0][tid] + P[1][tid] + P[2][tid] + P[3][tid]) * (1.f / ROI);
    __syncthreads();

    {
        float s0 = 0.f, s1 = 0.f, s2 = 0.f, s3 = 0.f;
        #pragma unroll 4
        for (int k = 0; k < 332; k += 4) {
            s0 += zs[k]     * Wl1[(size_t)k       * 256 + tid];
            s1 += zs[k + 1] * Wl1[(size_t)(k + 1) * 256 + tid];
            s2 += zs[k + 2] * Wl1[(size_t)(k + 2) * 256 + tid];
            s3 += zs[k + 3] * Wl1[(size_t)(k + 3) * 256 + tid];
        }
        h1[(size_t)b * 256 + tid] = bl1[tid] + ((s0 + s1) + (s2 + s3));
    }
}

// ======== K6: fc2 with fused batch stats ========
__global__ __launch_bounds__(128) void k_fc2s(
    const float* __restrict__ h1,
    const float* __restrict__ g4, const float* __restrict__ be4,
    const float* __restrict__ Wl2, const float* __restrict__ bl2,
    float* __restrict__ h2)
{
    const int b = blockIdx.x, tid = threadIdx.x;
    __shared__ float hs[256];
    float s0 = 0.f, q0 = 0.f, s1 = 0.f, q1 = 0.f;
    float s2 = 0.f, q2 = 0.f, s3 = 0.f, q3 = 0.f;
    for (int r = 0; r < NB; r += 2) {
        float a = h1[(size_t)r * 256 + tid];
        float c = h1[(size_t)r * 256 + tid + 128];
        float d = h1[(size_t)(r + 1) * 256 + tid];
        float e = h1[(size_t)(r + 1) * 256 + tid + 128];
        s0 += a; q0 += a * a;
        s1 += c; q1 += c * c;
        s2 += d; q2 += d * d;
        s3 += e; q3 += e * e;
    }
    {
        float ssA = s0 + s2, qqA = q0 + q2;
        float muA = ssA * (1.f / NB);
        float vaA = qqA * (1.f / NB) - muA * muA;
        float scA = g4[tid] * rsqrtf(vaA + EPSBN);
        float shA = be4[tid] - muA * scA;
        hs[tid] = lrelu(h1[(size_t)b * 256 + tid] * scA + shA);
        float ssB = s1 + s3, qqB = q1 + q3;
        float muB = ssB * (1.f / NB);
        float vaB = qqB * (1.f / NB) - muB * muB;
        float scB = g4[tid + 128] * rsqrtf(vaB + EPSBN);
        float shB = be4[tid + 128] - muB * scB;
        hs[tid + 128] = lrelu(h1[(size_t)b * 256 + tid + 128] * scB + shB);
    }
    __syncthreads();
    float s0b = 0.f, s1b = 0.f, s2b = 0.f, s3b = 0.f;
    #pragma unroll 4
    for (int k = 0; k < 256; k += 4) {
        s0b += hs[k]     * Wl2[(size_t)k       * 128 + tid];
        s1b += hs[k + 1] * Wl2[(size_t)(k + 1) * 128 + tid];
        s2b += hs[k + 2] * Wl2[(size_t)(k + 2) * 128 + tid];
        s3b += hs[k + 3] * Wl2[(size_t)(k + 3) * 128 + tid];
    }
    h2[(size_t)b * 128 + tid] = bl2[tid] + ((s0b + s1b) + (s2b + s3b));
}

// ======== K7: fc3 with fused batch stats (single block) ========
__global__ __launch_bounds__(128) void k_fc3s(
    const float* __restrict__ h2,
    const float* __restrict__ g5, const float* __restrict__ be5,
    const float* __restrict__ Wl3, const float* __restrict__ bl3,
    float* __restrict__ out)
{
    const int tid = threadIdx.x;
    __shared__ float T[64][133];
    float s0 = 0.f, q0 = 0.f, s1 = 0.f, q1 = 0.f;
    for (int r = 0; r < NB; r += 2) {
        float a = h2[(size_t)r * 128 + tid];
        float b = h2[(size_t)(r + 1) * 128 + tid];
        s0 += a; q0 += a * a;
        s1 += b; q1 += b * b;
    }
    float ss = s0 + s1, qq = q0 + q1;
    float mu  = ss * (1.f / NB);
    float var = qq * (1.f / NB) - mu * mu;
    float sc  = g5[tid] * rsqrtf(var + EPSBN);
    float sh  = be5[tid] - mu * sc;
    const float w3 = Wl3[tid];
    for (int r = 0; r < NB; ++r)
        T[r][tid] = lrelu(h2[(size_t)r * 128 + tid] * sc + sh) * w3;
    __syncthreads();
    if (tid < 64) {
        float a0 = 0.f, a1 = 0.f, a2 = 0.f, a3 = 0.f;
        #pragma unroll 4
        for (int c = 0; c < 128; c += 4) {
            a0 += T[tid][c];
            a1 += T[tid][c + 1];
            a2 += T[tid][c + 2];
            a3 += T[tid][c + 3];
        }
        out[tid] = bl3[0] + ((a0 + a1) + (a2 + a3));
    }
}

extern "C" void kernel_launch(void* const* d_in, const int* in_sizes, int n_in,
                              void* d_out, int out_size, void* d_ws, size_t ws_size,
                              hipStream_t stream)
{
    (void)in_sizes; (void)n_in; (void)out_size; (void)ws_size;
    const float* x   = (const float*)d_in[0];
    const int*   ei  = (const int*)d_in[1];
    const float* W1a = (const float*)d_in[3];
    const float* b1a = (const float*)d_in[4];
    const float* W1b = (const float*)d_in[5];
    const float* b1b = (const float*)d_in[6];
    const float* g1  = (const float*)d_in[7];
    const float* be1 = (const float*)d_in[8];
    const float* W2a = (const float*)d_in[9];
    const float* b2a = (const float*)d_in[10];
    const float* W2b = (const float*)d_in[11];
    const float* b2b = (const float*)d_in[12];
    const float* g2  = (const float*)d_in[13];
    const float* be2 = (const float*)d_in[14];
    const float* W3  = (const float*)d_in[15];
    const float* b3  = (const float*)d_in[16];
    const float* g3  = (const float*)d_in[17];
    const float* be3 = (const float*)d_in[18];
    const float* Wl1 = (const float*)d_in[19];
    const float* bl1 = (const float*)d_in[20];
    const float* g4  = (const float*)d_in[21];
    const float* be4 = (const float*)d_in[22];
    const float* Wl2 = (const float*)d_in[23];
    const float* bl2 = (const float*)d_in[24];
    const float* g5  = (const float*)d_in[25];
    const float* be5 = (const float*)d_in[26];
    const float* Wl3 = (const float*)d_in[27];
    const float* bl3 = (const float*)d_in[28];

    float* ws  = (float*)d_ws;
    float* u1  = ws;
    float* v1  = u1 + (size_t)NN * 32;
    float* u2  = v1 + (size_t)NN * 32;
    float* v2  = u2 + (size_t)NN * 32;
    float* u3  = v2 + (size_t)NN * 32;
    float* v3  = u3 + NN;
    float* sqv = v3 + NN;
    float* a1  = sqv + NN;
    float* a2  = a1 + (size_t)NN * 32;
    float* a3  = a2 + (size_t)NN * 32;
    float* h1  = a3 + NN;
    float* h2  = h1 + (size_t)NB * 256;
    float* part = h2 + (size_t)NB * 128;            // [64][128]
    int*   knn = (int*)(part + 64 * 128);
    unsigned short* Xh = (unsigned short*)(((uintptr_t)(knn + (size_t)NN * 32) + 255) & ~(uintptr_t)255);
    unsigned short* Xl = Xh + (size_t)64 * 17 * 9 * 512;
    unsigned short* Wfh = Xl + (size_t)64 * 17 * 9 * 512;
    unsigned short* Wfl = Wfh + (size_t)8 * 9 * 512;

    k_prep<<<PREP_PACK_BLOCKS + PREP_PACKW_BLOCKS + PREP_SCAL_BLOCKS, 256, 0, stream>>>(
        x, W1a, W2a, W3, b3, Xh, Xl, Wfh, Wfl, u3, v3, sqv);
    k_projdist<<<PD_DIST_BLOCKS + PD_PROJ_BLOCKS, 512, 0, stream>>>(
        Xh, Xl, Wfh, Wfl, b1a, b2a, sqv, u1, v1, u2, v2, knn);
    k_edge_fused<<<2 * NB * EDGE_GROUPS, 256, 0, stream>>>(
        u1, v1, W1b, b1b, ei, u2, v2, W2b, b2b, knn, u3, v3, a1, a2, a3);
    k_stats1<<<64, 256, 0, stream>>>(a1, a2, part);
    k_pool_fc1<<<NB, 256, 0, stream>>>(a1, a2, a3, part, g1, be1, g2, be2, g3, be3,
                                       Wl1, bl1, h1);
    k_fc2s<<<NB, 128, 0, stream>>>(h1, g4, be4, Wl2, bl2, h2);
    k_fc3s<<<1, 128, 0, stream>>>(h2, g5, be5, Wl3, bl3, (float*)d_out);
}